// Round 1
// 71.968 us; speedup vs baseline: 1.1766x; 1.1766x over previous
//
#include <hip/hip_runtime.h>

// DistillKL 'w' branch forward, B=64, C=1000, T=4.
// loss = -(T^2/B) * sum_{b,i} max(p_t,1e-7) * max(expt*log(min(p_s,1)), log(1e-7))
// where p = exp(x) / (choice * neg_sum + exp(x)), x = y/4,
//   t3[i] = (1/C) sum_k w[k]*relu(x[i]-x[k]),
//   choice = w*exp(-t3) + (1-w), neg_sum = sum_k (1-w[k])*exp(x[k]),
//   expt  = w*min(|(pt1+1)/2 - ps1|,1)^0.25 + (1-w)*min(|pt1/2 - ps1|,1).
//
// v2: k-loop was latency-bound at 1 wave/SIMD with 2000 dependent uniform
// ds_read_b32 per thread. Now: 512-thread blocks, k split into 4 quarters
// across thread groups (4 waves/SIMD TLP), float4 LDS reads (4x fewer,
// 8 in flight), C padded to 1024 with +1e30 (relu kills pad contributions).

#define BN 64
#define CN 1000
#define CPAD 1024
#define SPLITS 8
#define CHUNK 125          // i-values per block (8*125 = 1000)
#define THREADS 512
#define KQ (CPAD / 4)      // 256 k per thread-quarter
#define NEG_LOG_EPS -16.118095650958319f   // log(1e-7)

__global__ __launch_bounds__(THREADS) void distill_part(
    const float* __restrict__ ys, const float* __restrict__ yt,
    const float* __restrict__ w, float* __restrict__ part)
{
    const int b = blockIdx.x;
    const int s = blockIdx.y;
    const int tid = threadIdx.x;
    const int lane = tid & 63;
    const int wid = tid >> 6;          // 8 waves per block
    const int l = tid & 127;           // i-lane within block
    const int q = tid >> 7;            // k-quarter (0..3), wave-uniform

    __shared__ __align__(16) float xs[CPAD], xt[CPAD];     // x = y/4 (pad: 0)
    __shared__ __align__(16) float xsm[CPAD], xtm[CPAD];   // w? x : +1e30 (pad: 1e30)
    __shared__ float wsh[CPAD];                            // pad: 0
    __shared__ float ps_s[THREADS], ps_t[THREADS];         // per-thread quarter sums
    __shared__ float redns[16];                            // 8 waves x 2 negsums
    __shared__ float redterm[2];

    const float* ysr = ys + b * CN;
    const float* ytr = yt + b * CN;
    const float* wr  = w  + b * CN;

    // Phase 1: stage x, masked x, w into LDS; accumulate neg_sum.
    float ns_s = 0.f, ns_t = 0.f;
    #pragma unroll
    for (int k = tid; k < CPAD; k += THREADS) {
        if (k < CN) {
            float a  = ysr[k] * 0.25f;
            float c2 = ytr[k] * 0.25f;
            float wk = wr[k];
            xs[k] = a; xt[k] = c2; wsh[k] = wk;
            bool pos = (wk != 0.f);
            xsm[k] = pos ? a  : 1e30f;
            xtm[k] = pos ? c2 : 1e30f;
            float nw = 1.f - wk;
            ns_s += nw * expf(a);
            ns_t += nw * expf(c2);
        } else {
            xs[k] = 0.f; xt[k] = 0.f; wsh[k] = 0.f;
            xsm[k] = 1e30f; xtm[k] = 1e30f;
        }
    }
    #pragma unroll
    for (int off = 32; off > 0; off >>= 1) {
        ns_s += __shfl_down(ns_s, off);
        ns_t += __shfl_down(ns_t, off);
    }
    if (lane == 0) { redns[wid * 2] = ns_s; redns[wid * 2 + 1] = ns_t; }
    __syncthreads();
    float negsum_s = 0.f, negsum_t = 0.f;
    #pragma unroll
    for (int u = 0; u < 8; ++u) {
        negsum_s += redns[u * 2];
        negsum_t += redns[u * 2 + 1];
    }

    // Phase 2: each thread sums its k-quarter for one i.
    // i <= 7*125 + 127 = 1002 < CPAD, pad region initialized -> no garbage.
    const int i = s * CHUNK + l;
    const float xsi = xs[i], xti = xt[i];
    const float4* xsm4 = reinterpret_cast<const float4*>(xsm) + q * (KQ / 4);
    const float4* xtm4 = reinterpret_cast<const float4*>(xtm) + q * (KQ / 4);
    float as0 = 0.f, as1 = 0.f, at0 = 0.f, at1 = 0.f;
    #pragma unroll 4
    for (int j = 0; j < KQ / 4; ++j) {
        float4 vs = xsm4[j];
        float4 vt = xtm4[j];
        as0 += fmaxf(xsi - vs.x, 0.f);
        as1 += fmaxf(xsi - vs.y, 0.f);
        as0 += fmaxf(xsi - vs.z, 0.f);
        as1 += fmaxf(xsi - vs.w, 0.f);
        at0 += fmaxf(xti - vt.x, 0.f);
        at1 += fmaxf(xti - vt.y, 0.f);
        at0 += fmaxf(xti - vt.z, 0.f);
        at1 += fmaxf(xti - vt.w, 0.f);
    }
    ps_s[tid] = as0 + as1;
    ps_t[tid] = at0 + at1;
    __syncthreads();

    // Phase 3: threads 0..124 combine quarters and compute the loss term.
    float term = 0.f;
    if (tid < CHUNK) {
        const float acc_s = ps_s[tid] + ps_s[tid + 128] + ps_s[tid + 256] + ps_s[tid + 384];
        const float acc_t = ps_t[tid] + ps_t[tid + 128] + ps_t[tid + 256] + ps_t[tid + 384];
        const float t3s = acc_s * (1.0f / CN);
        const float t3t = acc_t * (1.0f / CN);
        const float wi = wsh[i];
        const float ch_s = wi * expf(-t3s) + (1.f - wi);
        const float ch_t = wi * expf(-t3t) + (1.f - wi);
        const float exs = expf(xsi), ext = expf(xti);
        const float p_s = exs / (ch_s * negsum_s + exs);
        const float p_t = ext / (ch_t * negsum_t + ext);
        const float ps1 = fminf(p_s, 1.f);
        const float pt1 = fminf(p_t, 1.f);
        const float vpos = fminf(fabsf((pt1 + 1.f) * 0.5f - ps1), 1.f);
        const float vneg = fminf(fabsf(pt1 * 0.5f - ps1), 1.f);
        const float expt = wi * sqrtf(sqrtf(vpos)) + (1.f - wi) * vneg;
        const float logps = fmaxf(expt * logf(ps1), NEG_LOG_EPS);
        term = fmaxf(p_t, 1e-7f) * logps;
    }
    #pragma unroll
    for (int off = 32; off > 0; off >>= 1) term += __shfl_down(term, off);
    if (wid < 2 && lane == 0) redterm[wid] = term;
    __syncthreads();
    if (tid == 0) part[b * SPLITS + s] = redterm[0] + redterm[1];
}

__global__ __launch_bounds__(64) void distill_final(
    const float* __restrict__ part, float* __restrict__ out)
{
    const int t = threadIdx.x;
    float v = 0.f;
    for (int j = t; j < BN * SPLITS; j += 64) v += part[j];
    #pragma unroll
    for (int off = 32; off > 0; off >>= 1) v += __shfl_down(v, off);
    if (t == 0) out[0] = -0.25f * v;    // -(T*T)/B = -16/64
}

extern "C" void kernel_launch(void* const* d_in, const int* in_sizes, int n_in,
                              void* d_out, int out_size, void* d_ws, size_t ws_size,
                              hipStream_t stream) {
    const float* ys = (const float*)d_in[0];
    const float* yt = (const float*)d_in[1];
    const float* w  = (const float*)d_in[2];
    float* out  = (float*)d_out;
    float* part = (float*)d_ws;   // BN*SPLITS floats

    dim3 grid(BN, SPLITS);
    distill_part<<<grid, THREADS, 0, stream>>>(ys, yt, w, part);
    distill_final<<<1, 64, 0, stream>>>(part, out);
}

// Round 2
// 68.452 us; speedup vs baseline: 1.2371x; 1.0514x over previous
//
#include <hip/hip_runtime.h>

// DistillKL 'w' branch forward, B=64, C=1000, T=4.
// loss = -(T^2/B) * sum_{b,i} max(p_t,1e-7) * max(expt*log(min(p_s,1)), log(1e-7))
// where p = exp(x) / (choice * neg_sum + exp(x)), x = y/4,
//   t3[i] = (1/C) sum_k w[k]*relu(x[i]-x[k]),
//   choice = w*exp(-t3) + (1-w), neg_sum = sum_k (1-w[k])*exp(x[k]),
//   expt  = w*min(|(pt1+1)/2 - ps1|,1)^0.25 + (1-w)*min(|pt1/2 - ps1|,1).
//
// v3: phase 2 was LDS-return-BW + VALU bound (~27 us). Two algebraic cuts:
//  (a) k-compaction: only w[k]!=0 contribute (masked +1e30 gave relu=0);
//      compact ~500 positives into a dense padded list -> 2x less loop work.
//  (b) i-blocking x2: 64 i-slots x 8 k-slices, each float4 reused for 2 i's
//      -> 2x fewer ds_read_b128 per unit work.

#define BN 64
#define CN 1000
#define CPAD 1024
#define SPLITS 8
#define CHUNK 125          // i-values per block (8*125 = 1000)
#define THREADS 512
#define NEG_LOG_EPS -16.118095650958319f   // log(1e-7)

__global__ __launch_bounds__(THREADS) void distill_part(
    const float* __restrict__ ys, const float* __restrict__ yt,
    const float* __restrict__ w, float* __restrict__ part)
{
    const int b = blockIdx.x;
    const int s = blockIdx.y;
    const int tid = threadIdx.x;
    const int lane = tid & 63;
    const int wid = tid >> 6;          // 8 waves per block

    __shared__ __align__(16) float xs[CPAD], xt[CPAD];     // x = y/4 (pad: 0)
    __shared__ __align__(16) float xsc[CPAD], xtc[CPAD];   // compacted positives (pad: 1e30)
    __shared__ float wsh[CPAD];                            // pad: 0
    __shared__ __align__(16) float ps0s[THREADS], ps1s[THREADS];  // slice partials, i0/i1
    __shared__ __align__(16) float ps0t[THREADS], ps1t[THREADS];
    __shared__ float redns[16];                            // 8 waves x 2 negsums
    __shared__ float redterm[2];
    __shared__ int mcnt;                                   // padded compacted count

    const float* ysr = ys + b * CN;
    const float* ytr = yt + b * CN;
    const float* wr  = w  + b * CN;

    // Phase 1: stage x, w into LDS; accumulate neg_sum.
    float ns_s = 0.f, ns_t = 0.f;
    #pragma unroll
    for (int k = tid; k < CPAD; k += THREADS) {
        if (k < CN) {
            float a  = ysr[k] * 0.25f;
            float c2 = ytr[k] * 0.25f;
            float wk = wr[k];
            xs[k] = a; xt[k] = c2; wsh[k] = wk;
            float nw = 1.f - wk;
            ns_s += nw * expf(a);
            ns_t += nw * expf(c2);
        } else {
            xs[k] = 0.f; xt[k] = 0.f; wsh[k] = 0.f;
        }
    }
    #pragma unroll
    for (int off = 32; off > 0; off >>= 1) {
        ns_s += __shfl_down(ns_s, off);
        ns_t += __shfl_down(ns_t, off);
    }
    if (lane == 0) { redns[wid * 2] = ns_s; redns[wid * 2 + 1] = ns_t; }
    __syncthreads();
    float negsum_s = 0.f, negsum_t = 0.f;
    #pragma unroll
    for (int u = 0; u < 8; ++u) {
        negsum_s += redns[u * 2];
        negsum_t += redns[u * 2 + 1];
    }

    // Phase 1b: wave 0 builds the compacted positive-k list (ascending k),
    // padded to a multiple of 32 with +1e30 (relu contributes 0).
    if (wid == 0) {
        int base = 0;
        for (int k0 = 0; k0 < CPAD; k0 += 64) {
            const int k = k0 + lane;
            const bool pos = (wsh[k] != 0.f);          // pad wsh==0 -> excluded
            const unsigned long long mask = __ballot(pos);
            const int pre = __popcll(mask & ((1ull << lane) - 1ull));
            if (pos) { xsc[base + pre] = xs[k]; xtc[base + pre] = xt[k]; }
            base += __popcll(mask);
        }
        const int mp = (base + 31) & ~31;
        for (int m = base + lane; m < mp; m += 64) { xsc[m] = 1e30f; xtc[m] = 1e30f; }
        if (lane == 0) mcnt = mp;
    }
    __syncthreads();

    // Phase 2: 64 i-slots x 8 k-slices; each thread handles 2 i's per float4.
    const int Mpad = mcnt;
    const int SL4  = Mpad >> 5;        // float4s per slice (Mpad/8/4), exact
    const int il = tid & 63;
    const int q  = tid >> 6;           // wave-uniform k-slice
    const int i0 = s * CHUNK + il;
    const bool has2 = (il < CHUNK - 64);   // il < 61
    const int i1 = has2 ? i0 + 64 : i0;
    const float xsi0 = xs[i0], xti0 = xt[i0];
    const float xsi1 = xs[i1], xti1 = xt[i1];
    const float4* s4 = reinterpret_cast<const float4*>(xsc) + q * SL4;
    const float4* t4 = reinterpret_cast<const float4*>(xtc) + q * SL4;
    float a0s = 0.f, a1s = 0.f, a0t = 0.f, a1t = 0.f;
    #pragma unroll 2
    for (int j = 0; j < SL4; ++j) {
        const float4 vs = s4[j];
        const float4 vt = t4[j];
        a0s += (fmaxf(xsi0 - vs.x, 0.f) + fmaxf(xsi0 - vs.y, 0.f))
             + (fmaxf(xsi0 - vs.z, 0.f) + fmaxf(xsi0 - vs.w, 0.f));
        a1s += (fmaxf(xsi1 - vs.x, 0.f) + fmaxf(xsi1 - vs.y, 0.f))
             + (fmaxf(xsi1 - vs.z, 0.f) + fmaxf(xsi1 - vs.w, 0.f));
        a0t += (fmaxf(xti0 - vt.x, 0.f) + fmaxf(xti0 - vt.y, 0.f))
             + (fmaxf(xti0 - vt.z, 0.f) + fmaxf(xti0 - vt.w, 0.f));
        a1t += (fmaxf(xti1 - vt.x, 0.f) + fmaxf(xti1 - vt.y, 0.f))
             + (fmaxf(xti1 - vt.z, 0.f) + fmaxf(xti1 - vt.w, 0.f));
    }
    ps0s[tid] = a0s; ps1s[tid] = a1s;
    ps0t[tid] = a0t; ps1t[tid] = a1t;
    __syncthreads();

    // Phase 3: threads 0..124 combine slice partials and compute the loss term.
    float term = 0.f;
    if (tid < CHUNK) {
        const int i = s * CHUNK + tid;
        const float* bs = (tid < 64) ? ps0s : ps1s;
        const float* bt = (tid < 64) ? ps0t : ps1t;
        const int off = tid & 63;
        float acc_s = 0.f, acc_t = 0.f;
        #pragma unroll
        for (int qq = 0; qq < 8; ++qq) {
            acc_s += bs[qq * 64 + off];
            acc_t += bt[qq * 64 + off];
        }
        const float t3s = acc_s * (1.0f / CN);
        const float t3t = acc_t * (1.0f / CN);
        const float wi = wsh[i];
        const float xsi = xs[i], xti = xt[i];
        const float ch_s = wi * expf(-t3s) + (1.f - wi);
        const float ch_t = wi * expf(-t3t) + (1.f - wi);
        const float exs = expf(xsi), ext = expf(xti);
        const float p_s = exs / (ch_s * negsum_s + exs);
        const float p_t = ext / (ch_t * negsum_t + ext);
        const float ps1 = fminf(p_s, 1.f);
        const float pt1 = fminf(p_t, 1.f);
        const float vpos = fminf(fabsf((pt1 + 1.f) * 0.5f - ps1), 1.f);
        const float vneg = fminf(fabsf(pt1 * 0.5f - ps1), 1.f);
        const float expt = wi * sqrtf(sqrtf(vpos)) + (1.f - wi) * vneg;
        const float logps = fmaxf(expt * logf(ps1), NEG_LOG_EPS);
        term = fmaxf(p_t, 1e-7f) * logps;
    }
    #pragma unroll
    for (int off = 32; off > 0; off >>= 1) term += __shfl_down(term, off);
    if (wid < 2 && lane == 0) redterm[wid] = term;
    __syncthreads();
    if (tid == 0) part[b * SPLITS + s] = redterm[0] + redterm[1];
}

__global__ __launch_bounds__(64) void distill_final(
    const float* __restrict__ part, float* __restrict__ out)
{
    const int t = threadIdx.x;
    float v = 0.f;
    for (int j = t; j < BN * SPLITS; j += 64) v += part[j];
    #pragma unroll
    for (int off = 32; off > 0; off >>= 1) v += __shfl_down(v, off);
    if (t == 0) out[0] = -0.25f * v;    // -(T*T)/B = -16/64
}

extern "C" void kernel_launch(void* const* d_in, const int* in_sizes, int n_in,
                              void* d_out, int out_size, void* d_ws, size_t ws_size,
                              hipStream_t stream) {
    const float* ys = (const float*)d_in[0];
    const float* yt = (const float*)d_in[1];
    const float* w  = (const float*)d_in[2];
    float* out  = (float*)d_out;
    float* part = (float*)d_ws;   // BN*SPLITS floats

    dim3 grid(BN, SPLITS);
    distill_part<<<grid, THREADS, 0, stream>>>(ys, yt, w, part);
    distill_final<<<1, 64, 0, stream>>>(part, out);
}